// Round 1
// baseline (146.672 us; speedup 1.0000x reference)
//
#include <hip/hip_runtime.h>
#include <hip/hip_bf16.h>

typedef __attribute__((ext_vector_type(8))) short short8;
typedef __attribute__((ext_vector_type(4))) float f32x4;

#define LOG2E 1.44269504088896f

__device__ __forceinline__ float bf2f(unsigned short b) {
    return __uint_as_float(((unsigned)b) << 16);
}
__device__ __forceinline__ unsigned short f2bf(float f) {
    __hip_bfloat16 h = __float2bfloat16(f);
    return __builtin_bit_cast(unsigned short, h);
}

// Kernel 1: seq_fts = x@W1 + b1 (f32 compute, bf16 store), F1 = log2e*(seq@a1+ba1), F2 likewise.
__global__ __launch_bounds__(256) void k_feats(
    const float* __restrict__ x, const float* __restrict__ W1,
    const float* __restrict__ b1, const float* __restrict__ a1,
    const float* __restrict__ ba1, const float* __restrict__ a2,
    const float* __restrict__ ba2,
    unsigned short* __restrict__ seqbf,
    float* __restrict__ F1, float* __restrict__ F2)
{
    __shared__ float W1s[4096];
    __shared__ float xs[4][64];
    const int t = threadIdx.x, w = t >> 6, lane = t & 63;
    for (int i = t; i < 1024; i += 256)
        ((float4*)W1s)[i] = ((const float4*)W1)[i];
    __syncthreads();
    float W1r[64];
    #pragma unroll
    for (int c = 0; c < 64; ++c) W1r[c] = W1s[c * 64 + lane];  // lane holds W1[:,lane]
    const int row = blockIdx.x * 4 + w;
    xs[w][lane] = x[(size_t)row * 64 + lane];
    float acc = 0.f;
    #pragma unroll
    for (int c4 = 0; c4 < 16; ++c4) {
        float4 xv = ((const float4*)xs[w])[c4];
        acc = fmaf(xv.x, W1r[4 * c4 + 0], acc);
        acc = fmaf(xv.y, W1r[4 * c4 + 1], acc);
        acc = fmaf(xv.z, W1r[4 * c4 + 2], acc);
        acc = fmaf(xv.w, W1r[4 * c4 + 3], acc);
    }
    const float s = acc + b1[lane];
    seqbf[(size_t)row * 64 + lane] = f2bf(s);
    float r1 = s * a1[lane];
    float r2 = s * a2[lane];
    #pragma unroll
    for (int off = 32; off; off >>= 1) {
        r1 += __shfl_xor(r1, off);
        r2 += __shfl_xor(r2, off);
    }
    if (lane == 0) {
        F1[row] = LOG2E * (r1 + ba1[0]);
        F2[row] = LOG2E * (r2 + ba2[0]);
    }
}

// Kernel 2: read adj once; produce bitmask + column sums S[b,j] = sum_i [adj]·exp(leaky(f1+f2)).
// Thread t handles 4 consecutive columns jbase..jbase+3; wave covers 256 columns.
// mask layout: [b][i][jg(0..15)][c(0..3)] u64; word (jg,c) bit l = adj[b][i][jg*256 + 4*l + c].
__global__ __launch_bounds__(256) void k_stats(
    const int* __restrict__ adj, const float* __restrict__ F1,
    const float* __restrict__ F2, float* __restrict__ S,
    unsigned long long* __restrict__ mask, int N)
{
    const int t = threadIdx.x;
    const int b = blockIdx.z;
    const int i0 = blockIdx.x * 64;
    const int jbase = blockIdx.y * 1024 + t * 4;
    const int* __restrict__ adjb = adj + (size_t)b * N * N;
    unsigned long long* __restrict__ maskb = mask + (size_t)b * N * 64;
    const float* __restrict__ F1b = F1 + b * N;
    const float* __restrict__ F2b = F2 + b * N;
    const float4 f1v = *(const float4*)(F1b + jbase);
    const int wjg4 = (jbase >> 8) << 2;  // uniform per wave: (by*4+w)*4
    float acc0 = 0.f, acc1 = 0.f, acc2 = 0.f, acc3 = 0.f;
    #pragma unroll 4
    for (int ii = 0; ii < 64; ++ii) {
        const int i = i0 + ii;
        const int4 a = *(const int4*)(adjb + (size_t)i * N + jbase);
        const float f2i = F2b[i];
        const unsigned long long m0 = __ballot(a.x > 0);
        const unsigned long long m1 = __ballot(a.y > 0);
        const unsigned long long m2 = __ballot(a.z > 0);
        const unsigned long long m3 = __ballot(a.w > 0);
        float u, mx;
        u = f1v.x + f2i; mx = fmaxf(u, 0.01f * u);
        acc0 += (a.x > 0) ? __builtin_amdgcn_exp2f(mx) : 0.f;
        u = f1v.y + f2i; mx = fmaxf(u, 0.01f * u);
        acc1 += (a.y > 0) ? __builtin_amdgcn_exp2f(mx) : 0.f;
        u = f1v.z + f2i; mx = fmaxf(u, 0.01f * u);
        acc2 += (a.z > 0) ? __builtin_amdgcn_exp2f(mx) : 0.f;
        u = f1v.w + f2i; mx = fmaxf(u, 0.01f * u);
        acc3 += (a.w > 0) ? __builtin_amdgcn_exp2f(mx) : 0.f;
        if ((t & 63) == 0) {
            unsigned long long* dst = maskb + (size_t)i * 64 + wjg4;
            dst[0] = m0; dst[1] = m1; dst[2] = m2; dst[3] = m3;
        }
    }
    atomicAdd(&S[b * N + jbase + 0], acc0);
    atomicAdd(&S[b * N + jbase + 1], acc1);
    atomicAdd(&S[b * N + jbase + 2], acc2);
    atomicAdd(&S[b * N + jbase + 3], acc3);
}

// Kernel 3: seqTg[b][f][j] = seqbf[b][j][f] * (1/S[b,j])  (transpose + fold softmax denom into B)
__global__ __launch_bounds__(256) void k_transpose(
    const unsigned short* __restrict__ seqbf, const float* __restrict__ S,
    unsigned short* __restrict__ seqTg, int N)
{
    __shared__ unsigned short tile[64][65];
    const int t = threadIdx.x, sub = t >> 6, lane = t & 63;
    const int b = blockIdx.y;
    const int n0 = blockIdx.x * 64;
    const unsigned short* src = seqbf + ((size_t)b * N + n0) * 64;
    #pragma unroll
    for (int rr = 0; rr < 16; ++rr) {
        const int r = rr * 4 + sub;
        tile[r][lane] = src[r * 64 + lane];
    }
    const float Sv = S[b * N + n0 + lane];
    const float g = Sv > 0.f ? 1.f / Sv : 0.f;  // column j = n0+lane
    __syncthreads();
    unsigned short* dstb = seqTg + (size_t)b * 64 * N;
    #pragma unroll
    for (int ff = 0; ff < 16; ++ff) {
        const int f = ff * 4 + sub;
        const float v = bf2f(tile[lane][f]) * g;
        dstb[(size_t)f * N + n0 + lane] = f2bf(v);
    }
}

// Kernel 4: out[b][i][f] = elu( sum_j w[i,j] * seqTg[f][j] ), w generated in-register from bitmask.
// Block: 4 waves; each wave = 16 rows (i0..i0+15) x 64 f, over its K-quarter; LDS combine + fused ELU.
__global__ __launch_bounds__(256) void k_attn_mm(
    const unsigned long long* __restrict__ mask,
    const float* __restrict__ F1, const float* __restrict__ F2,
    const unsigned short* __restrict__ seqTg,
    float* __restrict__ out, int N)
{
    __shared__ float part[4][1024];
    const int t = threadIdx.x, w = t >> 6, l = t & 63;
    const int b = blockIdx.y;
    const int i0 = blockIdx.x * 16;
    const int mrow = l & 15;   // A-row / output row offset
    const int koff = l >> 4;   // k-group (8 elements each)
    const int i = i0 + mrow;
    const float F2i = F2[b * N + i];
    const float* __restrict__ F1b = F1 + b * N;
    const unsigned long long* __restrict__ mrowp = mask + (size_t)(b * N + i) * 64;
    const unsigned short* __restrict__ Tb = seqTg + (size_t)b * 64 * N;
    f32x4 acc0 = {0.f, 0.f, 0.f, 0.f}, acc1 = acc0, acc2 = acc0, acc3 = acc0;
    const int kq0 = w * (N >> 2);
    for (int kc = 0; kc < (N >> 10); ++kc) {
        const int jb_base = kq0 + kc * 256;
        const unsigned long long* mw = mrowp + ((jb_base >> 8) << 2);
        const ulonglong2 mwa = *(const ulonglong2*)(mw);
        const ulonglong2 mwb = *(const ulonglong2*)(mw + 2);
        const unsigned long long mw0 = mwa.x, mw1 = mwa.y, mw2 = mwb.x, mw3 = mwb.y;
        #pragma unroll
        for (int r = 0; r < 8; ++r) {
            const int jb = jb_base + r * 32;
            const int j0l = jb + koff * 8;
            const float4 fa = *(const float4*)(F1b + j0l);
            const float4 fbv = *(const float4*)(F1b + j0l + 4);
            const int sb = r * 8 + koff * 2;
            const float fv[8] = {fa.x, fa.y, fa.z, fa.w, fbv.x, fbv.y, fbv.z, fbv.w};
            float wv[8];
            #pragma unroll
            for (int e = 0; e < 8; ++e) {
                const unsigned long long mword =
                    (e & 3) == 0 ? mw0 : (e & 3) == 1 ? mw1 : (e & 3) == 2 ? mw2 : mw3;
                const int bit = (int)((mword >> (sb + (e >> 2))) & 1ull);
                const float u = fv[e] + F2i;
                const float mx = fmaxf(u, 0.01f * u);
                const float arg = bit ? mx : -1e30f;
                wv[e] = __builtin_amdgcn_exp2f(arg);
            }
            short8 afrag;
            #pragma unroll
            for (int e = 0; e < 8; ++e) afrag[e] = (short)f2bf(wv[e]);
            const short8 b0 = *(const short8*)(Tb + (size_t)(0 * 16 + mrow) * N + j0l);
            const short8 b1 = *(const short8*)(Tb + (size_t)(1 * 16 + mrow) * N + j0l);
            const short8 b2 = *(const short8*)(Tb + (size_t)(2 * 16 + mrow) * N + j0l);
            const short8 b3 = *(const short8*)(Tb + (size_t)(3 * 16 + mrow) * N + j0l);
            acc0 = __builtin_amdgcn_mfma_f32_16x16x32_bf16(afrag, b0, acc0, 0, 0, 0);
            acc1 = __builtin_amdgcn_mfma_f32_16x16x32_bf16(afrag, b1, acc1, 0, 0, 0);
            acc2 = __builtin_amdgcn_mfma_f32_16x16x32_bf16(afrag, b2, acc2, 0, 0, 0);
            acc3 = __builtin_amdgcn_mfma_f32_16x16x32_bf16(afrag, b3, acc3, 0, 0, 0);
        }
    }
    #pragma unroll
    for (int rg = 0; rg < 4; ++rg) {
        const int m = koff * 4 + rg;
        part[w][m * 64 + 0 * 16 + mrow] = acc0[rg];
        part[w][m * 64 + 1 * 16 + mrow] = acc1[rg];
        part[w][m * 64 + 2 * 16 + mrow] = acc2[rg];
        part[w][m * 64 + 3 * 16 + mrow] = acc3[rg];
    }
    __syncthreads();
    const float4 v0 = *(const float4*)&part[0][t * 4];
    const float4 v1 = *(const float4*)&part[1][t * 4];
    const float4 v2 = *(const float4*)&part[2][t * 4];
    const float4 v3 = *(const float4*)&part[3][t * 4];
    float4 r;
    r.x = v0.x + v1.x + v2.x + v3.x;
    r.y = v0.y + v1.y + v2.y + v3.y;
    r.z = v0.z + v1.z + v2.z + v3.z;
    r.w = v0.w + v1.w + v2.w + v3.w;
    r.x = r.x > 0.f ? r.x : __builtin_amdgcn_exp2f(r.x * LOG2E) - 1.f;
    r.y = r.y > 0.f ? r.y : __builtin_amdgcn_exp2f(r.y * LOG2E) - 1.f;
    r.z = r.z > 0.f ? r.z : __builtin_amdgcn_exp2f(r.z * LOG2E) - 1.f;
    r.w = r.w > 0.f ? r.w : __builtin_amdgcn_exp2f(r.w * LOG2E) - 1.f;
    *(float4*)(out + (size_t)(b * N + i0) * 64 + t * 4) = r;
}

extern "C" void kernel_launch(void* const* d_in, const int* in_sizes, int n_in,
                              void* d_out, int out_size, void* d_ws, size_t ws_size,
                              hipStream_t stream) {
    const float* x   = (const float*)d_in[0];
    const int*   adj = (const int*)d_in[1];
    const float* W1  = (const float*)d_in[2];
    const float* b1  = (const float*)d_in[3];
    const float* a1  = (const float*)d_in[4];
    const float* ba1 = (const float*)d_in[5];
    const float* a2  = (const float*)d_in[6];
    const float* ba2 = (const float*)d_in[7];
    float* out = (float*)d_out;

    const int F = in_sizes[3];                       // 64
    const int C = in_sizes[2] / F;                   // 64
    const long xs = in_sizes[0], as = in_sizes[1];
    const int N = (int)(as / (xs / C));              // 4096
    const int B = (int)(xs / ((long)N * C));         // 4
    const size_t BN = (size_t)B * N;

    char* p = (char*)d_ws;
    unsigned short* seqbf = (unsigned short*)p; p += BN * 64 * 2;
    unsigned short* seqTg = (unsigned short*)p; p += BN * 64 * 2;
    float* F1 = (float*)p; p += BN * 4;
    float* F2 = (float*)p; p += BN * 4;
    float* S  = (float*)p; p += BN * 4;
    unsigned long long* mask = (unsigned long long*)p; p += BN * 64 * 8;

    hipMemsetAsync(S, 0, BN * 4, stream);
    k_feats<<<dim3((unsigned)(BN / 4)), 256, 0, stream>>>(x, W1, b1, a1, ba1, a2, ba2,
                                                          seqbf, F1, F2);
    k_stats<<<dim3(N / 64, N / 1024, B), 256, 0, stream>>>(adj, F1, F2, S, mask, N);
    k_transpose<<<dim3(N / 64, B), 256, 0, stream>>>(seqbf, S, seqTg, N);
    k_attn_mm<<<dim3(N / 16, B), 256, 0, stream>>>(mask, F1, F2, seqTg, out, N);
}